// Round 2
// baseline (3996.305 us; speedup 1.0000x reference)
//
#include <hip/hip_runtime.h>
#include <math.h>

static constexpr int N_NODES = 100000;
static constexpr int N_EDGES = 1600000;
static constexpr int E_TOT   = N_NODES + N_EDGES;   // edges + self-loops
static constexpr int D   = 512;
static constexpr int FIN = 182;
static constexpr float NEG_SLOPE = 0.2f;
static constexpr float LN_EPS = 1e-5f;

// ---------------- bf16 helpers (storage type: unsigned short) ----------------
__device__ __forceinline__ float bf2f(unsigned int u16) {
  unsigned int x = u16 << 16;
  return __builtin_bit_cast(float, x);
}
__device__ __forceinline__ unsigned short f2bf(float f) {
  unsigned int x = __builtin_bit_cast(unsigned int, f);
  x += 0x7fffu + ((x >> 16) & 1u);   // round-to-nearest-even
  return (unsigned short)(x >> 16);
}
// unpack uint32 holding two bf16 (little-endian: low ushort = even element)
__device__ __forceinline__ void unpack2(unsigned int w, float& lo, float& hi) {
  lo = __builtin_bit_cast(float, w << 16);
  hi = __builtin_bit_cast(float, w & 0xffff0000u);
}

// ---------------------------------------------------------------------------
// init + edge-index dtype probe.
// If edge_index is stored as int64, every odd 32-bit word of the first 2E
// words (the src row as int64) is zero. If int32, those words are real node
// ids (nonzero w.p. 1-1e-5 each). flag==0 => int64 layout.
// ---------------------------------------------------------------------------
__global__ __launch_bounds__(256) void k_init(int* __restrict__ deg,
                                              int* __restrict__ counter,
                                              int* __restrict__ flag) {
  int i = blockIdx.x * 256 + threadIdx.x;
  if (i < N_NODES) deg[i] = 0;
  if (i == 0) { *counter = 0; *flag = 0; }
}

__global__ __launch_bounds__(256) void k_detect(const int* __restrict__ ei,
                                                int* __restrict__ flag) {
  int i = blockIdx.x * 256 + threadIdx.x;
  bool nz = (i < N_EDGES) && (ei[2 * i + 1] != 0);
  if (__any(nz) && (threadIdx.x & 63) == 0) atomicOr(flag, 1);
}

__device__ __forceinline__ int edge_src(const int* ei, int f, int i) {
  return f ? ei[i] : ei[2 * i];
}
__device__ __forceinline__ int edge_dst(const int* ei, int f, int i) {
  return f ? ei[N_EDGES + i] : ei[2 * (N_EDGES + i)];
}

// ---------------------------------------------------------------------------
// CSR build grouped by dst (range order irrelevant -> atomic range alloc)
// ---------------------------------------------------------------------------
__global__ __launch_bounds__(256) void k_count(const int* __restrict__ ei,
                                               const int* __restrict__ flag,
                                               int* __restrict__ deg) {
  int i = blockIdx.x * 256 + threadIdx.x;
  if (i >= E_TOT) return;
  int f = *flag;
  int d = (i < N_EDGES) ? edge_dst(ei, f, i) : (i - N_EDGES);
  atomicAdd(deg + d, 1);
}

__global__ __launch_bounds__(256) void k_alloc(const int* __restrict__ deg,
                                               int* __restrict__ off,
                                               int* __restrict__ pos,
                                               int* __restrict__ counter) {
  int i = blockIdx.x * 256 + threadIdx.x;
  if (i >= N_NODES) return;
  int r = atomicAdd(counter, deg[i]);
  off[i] = r;
  pos[i] = r;
}

__global__ __launch_bounds__(256) void k_fill(const int* __restrict__ ei,
                                              const int* __restrict__ flag,
                                              int* __restrict__ pos,
                                              int* __restrict__ csr_src) {
  int i = blockIdx.x * 256 + threadIdx.x;
  if (i >= E_TOT) return;
  int f = *flag;
  int s, d;
  if (i < N_EDGES) { s = edge_src(ei, f, i); d = edge_dst(ei, f, i); }
  else             { s = d = i - N_EDGES; }
  int slot = atomicAdd(pos + d, 1);
  csr_src[slot] = s;
}

// ---------------------------------------------------------------------------
// fp32-accumulate GEMM: C[M,NC] = A[M,K] @ B[K,NC] (+bias+relu), C is bf16.
// A is fp32 (layer 1) or bf16 (layer 2 / classifier). 128x128 tile, 256 thr.
// ---------------------------------------------------------------------------
__device__ __forceinline__ float ldA(const float* A, size_t i) { return A[i]; }
__device__ __forceinline__ float ldA(const unsigned short* A, size_t i) { return bf2f(A[i]); }

template<typename AT, bool BIAS_RELU>
__global__ __launch_bounds__(256)
void gemm_k(const AT* __restrict__ A, const float* __restrict__ B,
            const float* __restrict__ bias, unsigned short* __restrict__ C,
            int M, int K, int NC)
{
  __shared__ float As[16][132];
  __shared__ float Bs[16][132];
  const int t  = threadIdx.x;
  const int tx = t & 15;
  const int ty = t >> 4;
  const int bm = blockIdx.y * 128;
  const int bn = blockIdx.x * 128;

  float acc[8][8];
#pragma unroll
  for (int i = 0; i < 8; ++i)
#pragma unroll
    for (int j = 0; j < 8; ++j) acc[i][j] = 0.f;

  for (int k0 = 0; k0 < K; k0 += 16) {
#pragma unroll
    for (int i = 0; i < 8; ++i) {
      int idx = t + i * 256;                 // 0..2047
      int m = idx >> 4, k = idx & 15;
      int gm = bm + m, gk = k0 + k;
      As[k][m] = (gm < M && gk < K) ? ldA(A, (size_t)gm * K + gk) : 0.f;
      int n = idx & 127, k2 = idx >> 7;
      int gk2 = k0 + k2;
      Bs[k2][n] = (gk2 < K) ? B[(size_t)gk2 * NC + bn + n] : 0.f;
    }
    __syncthreads();
#pragma unroll
    for (int k = 0; k < 16; ++k) {
      float4 a0 = *(const float4*)&As[k][ty * 8];
      float4 a1 = *(const float4*)&As[k][ty * 8 + 4];
      float4 b0 = *(const float4*)&Bs[k][tx * 8];
      float4 b1 = *(const float4*)&Bs[k][tx * 8 + 4];
      float av[8] = {a0.x,a0.y,a0.z,a0.w,a1.x,a1.y,a1.z,a1.w};
      float bv[8] = {b0.x,b0.y,b0.z,b0.w,b1.x,b1.y,b1.z,b1.w};
#pragma unroll
      for (int i = 0; i < 8; ++i)
#pragma unroll
        for (int j = 0; j < 8; ++j)
          acc[i][j] += av[i] * bv[j];
    }
    __syncthreads();
  }

  const int gn0 = bn + tx * 8;
#pragma unroll
  for (int i = 0; i < 8; ++i) {
    int gm = bm + ty * 8 + i;
    if (gm >= M) continue;
    unsigned short us[8];
#pragma unroll
    for (int j = 0; j < 8; ++j) {
      float v = acc[i][j];
      if (BIAS_RELU) { v += bias[gn0 + j]; v = fmaxf(v, 0.f); }
      us[j] = f2bf(v);
    }
    uint4 w;
    w.x = (unsigned int)us[0] | ((unsigned int)us[1] << 16);
    w.y = (unsigned int)us[2] | ((unsigned int)us[3] << 16);
    w.z = (unsigned int)us[4] | ((unsigned int)us[5] << 16);
    w.w = (unsigned int)us[6] | ((unsigned int)us[7] << 16);
    *(uint4*)&C[(size_t)gm * NC + gn0] = w;
  }
}

// ---------------------------------------------------------------------------
// Per-node attention dots on bf16 h: s[n,h] = sum_c h[n,h*128+c]*a[h,c]
// One wave per node; 16 lanes per head; lane covers 8 contiguous elements.
// ---------------------------------------------------------------------------
__global__ __launch_bounds__(256) void k_sdots(const unsigned short* __restrict__ h,
                                               const float* __restrict__ a_src,
                                               const float* __restrict__ a_dst,
                                               float* __restrict__ s_src,
                                               float* __restrict__ s_dst) {
  int node = blockIdx.x * 4 + (threadIdx.x >> 6);
  int lane = threadIdx.x & 63;
  if (node >= N_NODES) return;
  uint4 w = ((const uint4*)(h + (size_t)node * D))[lane];
  float v[8];
  unpack2(w.x, v[0], v[1]); unpack2(w.y, v[2], v[3]);
  unpack2(w.z, v[4], v[5]); unpack2(w.w, v[6], v[7]);
  const float4* as = (const float4*)a_src;   // [4,128] flat
  const float4* ad = (const float4*)a_dst;
  float4 s0 = as[lane*2], s1 = as[lane*2+1];
  float4 d0 = ad[lane*2], d1 = ad[lane*2+1];
  float ps = v[0]*s0.x + v[1]*s0.y + v[2]*s0.z + v[3]*s0.w
           + v[4]*s1.x + v[5]*s1.y + v[6]*s1.z + v[7]*s1.w;
  float pd = v[0]*d0.x + v[1]*d0.y + v[2]*d0.z + v[3]*d0.w
           + v[4]*d1.x + v[5]*d1.y + v[6]*d1.z + v[7]*d1.w;
#pragma unroll
  for (int o = 1; o < 16; o <<= 1) {
    ps += __shfl_xor(ps, o);
    pd += __shfl_xor(pd, o);
  }
  if ((lane & 15) == 0) {
    int hh = lane >> 4;
    s_src[node*4 + hh] = ps;
    s_dst[node*4 + hh] = pd;
  }
}

// ---------------------------------------------------------------------------
// Fused segment-softmax + weighted aggregation + bias + LayerNorm + ELU.
// One wave per dst node. Softmax stats: lanes stride (edge,head) pairs with
// hh = lane&3 stable; per-head butterflies over xor 4..32. Gather pass:
// lane holds out elems lane*8..lane*8+7 (head = lane>>4), alpha recomputed
// inline from cached s_src gathers. No per-edge alpha materialization.
// ---------------------------------------------------------------------------
__global__ __launch_bounds__(256) void k_aggregate(const unsigned short* __restrict__ h,
                                                   const int* __restrict__ csr_src,
                                                   const int* __restrict__ off,
                                                   const int* __restrict__ deg,
                                                   const float* __restrict__ s_src,
                                                   const float* __restrict__ s_dst,
                                                   const float* __restrict__ bvec,
                                                   const float* __restrict__ gvec,
                                                   const float* __restrict__ bevec,
                                                   unsigned short* __restrict__ out) {
  int node = blockIdx.x * 4 + (threadIdx.x >> 6);
  int lane = threadIdx.x & 63;
  if (node >= N_NODES) return;
  int o = off[node], cnt = deg[node];
  int total = cnt * 4;
  int hh = lane & 3;
  float sd = s_dst[(size_t)node*4 + hh];

  // pass 1: per-head max
  float m = -1e30f;
  for (int idx = lane; idx < total; idx += 64) {
    int s = csr_src[o + (idx >> 2)];
    float e = s_src[(size_t)s*4 + hh] + sd;
    e = (e > 0.f) ? e : NEG_SLOPE * e;
    m = fmaxf(m, e);
  }
#pragma unroll
  for (int o2 = 4; o2 < 64; o2 <<= 1) m = fmaxf(m, __shfl_xor(m, o2));

  // pass 2: per-head sum of exp (re-gather; addresses are hot in L1/L2)
  float sum = 0.f;
  for (int idx = lane; idx < total; idx += 64) {
    int s = csr_src[o + (idx >> 2)];
    float e = s_src[(size_t)s*4 + hh] + sd;
    e = (e > 0.f) ? e : NEG_SLOPE * e;
    sum += expf(e - m);
  }
#pragma unroll
  for (int o2 = 4; o2 < 64; o2 <<= 1) sum += __shfl_xor(sum, o2);

  // broadcast this lane's head stats (lanes 0..3 hold heads 0..3)
  int head = lane >> 4;
  float mH   = __shfl(m, head);
  float invH = 1.f / __shfl(sum, head);
  float sdH  = s_dst[(size_t)node*4 + head];

  // pass 3: gather + weighted accumulate
  float acc[8] = {0.f,0.f,0.f,0.f,0.f,0.f,0.f,0.f};
  for (int j = 0; j < cnt; ++j) {
    int s = csr_src[o + j];
    float e = s_src[(size_t)s*4 + head] + sdH;
    e = (e > 0.f) ? e : NEG_SLOPE * e;
    float p = expf(e - mH) * invH;
    uint4 w = ((const uint4*)(h + (size_t)s * D))[lane];
    float v[8];
    unpack2(w.x, v[0], v[1]); unpack2(w.y, v[2], v[3]);
    unpack2(w.z, v[4], v[5]); unpack2(w.w, v[6], v[7]);
#pragma unroll
    for (int k = 0; k < 8; ++k) acc[k] += p * v[k];
  }

  // + bias, then LayerNorm stats over all 512 (full-wave butterflies)
  const float4* bb = (const float4*)bvec;
  float4 b0 = bb[lane*2], b1 = bb[lane*2+1];
  float bl[8] = {b0.x,b0.y,b0.z,b0.w,b1.x,b1.y,b1.z,b1.w};
#pragma unroll
  for (int k = 0; k < 8; ++k) acc[k] += bl[k];

  float ps = 0.f, pq = 0.f;
#pragma unroll
  for (int k = 0; k < 8; ++k) { ps += acc[k]; pq += acc[k]*acc[k]; }
#pragma unroll
  for (int o2 = 1; o2 < 64; o2 <<= 1) {
    ps += __shfl_xor(ps, o2);
    pq += __shfl_xor(pq, o2);
  }
  float mu  = ps * (1.f/512.f);
  float var = pq * (1.f/512.f) - mu*mu;
  float rstd = rsqrtf(var + LN_EPS);

  const float4* gg = (const float4*)gvec;
  const float4* ee = (const float4*)bevec;
  float4 g0 = gg[lane*2], g1 = gg[lane*2+1];
  float4 e0 = ee[lane*2], e1 = ee[lane*2+1];
  float gs[8] = {g0.x,g0.y,g0.z,g0.w,g1.x,g1.y,g1.z,g1.w};
  float es[8] = {e0.x,e0.y,e0.z,e0.w,e1.x,e1.y,e1.z,e1.w};

  unsigned short us[8];
#pragma unroll
  for (int k = 0; k < 8; ++k) {
    float y = (acc[k] - mu) * rstd * gs[k] + es[k];
    y = (y > 0.f) ? y : expm1f(y);
    us[k] = f2bf(y);
  }
  uint4 w;
  w.x = (unsigned int)us[0] | ((unsigned int)us[1] << 16);
  w.y = (unsigned int)us[2] | ((unsigned int)us[3] << 16);
  w.z = (unsigned int)us[4] | ((unsigned int)us[5] << 16);
  w.w = (unsigned int)us[6] | ((unsigned int)us[7] << 16);
  ((uint4*)(out + (size_t)node * D))[lane] = w;
}

// ---------------------------------------------------------------------------
// Final projection: out[n,0:2] = z[n,:] @ Wc2[512,2] + bc2 (z is bf16)
// ---------------------------------------------------------------------------
__global__ __launch_bounds__(256) void k_final(const unsigned short* __restrict__ z,
                                               const float* __restrict__ Wc2,
                                               const float* __restrict__ bc2,
                                               float* __restrict__ out) {
  int node = blockIdx.x * 4 + (threadIdx.x >> 6);
  int lane = threadIdx.x & 63;
  if (node >= N_NODES) return;
  uint4 w = ((const uint4*)(z + (size_t)node * D))[lane];
  float zv[8];
  unpack2(w.x, zv[0], zv[1]); unpack2(w.y, zv[2], zv[3]);
  unpack2(w.z, zv[4], zv[5]); unpack2(w.w, zv[6], zv[7]);
  const float* wr = Wc2 + (size_t)lane * 16;   // rows lane*8..lane*8+7, 2 cols
  float a0 = 0.f, a1 = 0.f;
#pragma unroll
  for (int k = 0; k < 8; ++k) {
    a0 += zv[k] * wr[k*2];
    a1 += zv[k] * wr[k*2+1];
  }
#pragma unroll
  for (int o2 = 1; o2 < 64; o2 <<= 1) {
    a0 += __shfl_xor(a0, o2);
    a1 += __shfl_xor(a1, o2);
  }
  if (lane == 0) {
    out[(size_t)node*2]     = a0 + bc2[0];
    out[(size_t)node*2 + 1] = a1 + bc2[1];
  }
}

// ---------------------------------------------------------------------------
extern "C" void kernel_launch(void* const* d_in, const int* in_sizes, int n_in,
                              void* d_out, int out_size, void* d_ws, size_t ws_size,
                              hipStream_t stream) {
  const float* x      = (const float*)d_in[0];
  const int*   ei     = (const int*)  d_in[1];
  const float* W1     = (const float*)d_in[2];
  const float* a_src1 = (const float*)d_in[3];
  const float* a_dst1 = (const float*)d_in[4];
  const float* b1     = (const float*)d_in[5];
  const float* g1     = (const float*)d_in[6];
  const float* be1    = (const float*)d_in[7];
  const float* W2     = (const float*)d_in[8];
  const float* a_src2 = (const float*)d_in[9];
  const float* a_dst2 = (const float*)d_in[10];
  const float* b2     = (const float*)d_in[11];
  const float* g2     = (const float*)d_in[12];
  const float* be2    = (const float*)d_in[13];
  const float* Wc1    = (const float*)d_in[14];
  const float* bc1    = (const float*)d_in[15];
  const float* Wc2    = (const float*)d_in[16];
  const float* bc2    = (const float*)d_in[17];
  float* outp = (float*)d_out;

  char* p = (char*)d_ws;
  auto alloc = [&](size_t bytes) {
    char* r = p;
    p += (bytes + 255) & ~(size_t)255;
    return r;
  };
  unsigned short* hbuf = (unsigned short*)alloc((size_t)N_NODES * D * 2); // 102.4 MB
  unsigned short* obuf = (unsigned short*)alloc((size_t)N_NODES * D * 2); // 102.4 MB
  int*   csr_src = (int*)  alloc((size_t)E_TOT * 4);                      // 6.8 MB
  int*   deg     = (int*)  alloc((size_t)N_NODES * 4);
  int*   off     = (int*)  alloc((size_t)N_NODES * 4);
  int*   pos     = (int*)  alloc((size_t)N_NODES * 4);
  int*   counter = (int*)  alloc(256);
  int*   flag    = (int*)  alloc(256);
  float* s_src   = (float*)alloc((size_t)N_NODES * 4 * 4);
  float* s_dst   = (float*)alloc((size_t)N_NODES * 4 * 4);
  // total ~= 216 MB

  const int EB = (E_TOT + 255) / 256;
  const int NB = (N_NODES + 255) / 256;
  const int DB = (N_EDGES + 255) / 256;
  const int NW = (N_NODES + 3) / 4;        // one wave per node, 4 waves/block
  dim3 gg(4, (N_NODES + 127) / 128);

  // init + dtype probe + CSR build (shared by both layers)
  k_init  <<<NB, 256, 0, stream>>>(deg, counter, flag);
  k_detect<<<DB, 256, 0, stream>>>(ei, flag);
  k_count <<<EB, 256, 0, stream>>>(ei, flag, deg);
  k_alloc <<<NB, 256, 0, stream>>>(deg, off, pos, counter);
  k_fill  <<<EB, 256, 0, stream>>>(ei, flag, pos, csr_src);

  // Layer 1
  gemm_k<float, false><<<gg, 256, 0, stream>>>(x, W1, nullptr, hbuf, N_NODES, FIN, D);
  k_sdots    <<<NW, 256, 0, stream>>>(hbuf, a_src1, a_dst1, s_src, s_dst);
  k_aggregate<<<NW, 256, 0, stream>>>(hbuf, csr_src, off, deg, s_src, s_dst, b1, g1, be1, obuf);

  // Layer 2
  gemm_k<unsigned short, false><<<gg, 256, 0, stream>>>(obuf, W2, nullptr, hbuf, N_NODES, D, D);
  k_sdots    <<<NW, 256, 0, stream>>>(hbuf, a_src2, a_dst2, s_src, s_dst);
  k_aggregate<<<NW, 256, 0, stream>>>(hbuf, csr_src, off, deg, s_src, s_dst, b2, g2, be2, obuf);

  // Classifier
  gemm_k<unsigned short, true><<<gg, 256, 0, stream>>>(obuf, Wc1, bc1, hbuf, N_NODES, D, D);
  k_final    <<<NW, 256, 0, stream>>>(hbuf, Wc2, bc2, outp);
}

// Round 3
// 1536.351 us; speedup vs baseline: 2.6012x; 2.6012x over previous
//
#include <hip/hip_runtime.h>
#include <math.h>

static constexpr int N_NODES = 100000;
static constexpr int N_EDGES = 1600000;
static constexpr int E_TOT   = N_NODES + N_EDGES;   // edges + self-loops
static constexpr int D   = 512;
static constexpr int FIN = 182;
static constexpr int K1P = 192;                     // FIN padded to mult of 32
static constexpr int M_PAD = 100096;                // 782 * 128
static constexpr float NEG_SLOPE = 0.2f;
static constexpr float LN_EPS = 1e-5f;

typedef __attribute__((ext_vector_type(8))) short short8;
typedef __attribute__((ext_vector_type(4))) float floatx4;

// ---------------- bf16 helpers (storage type: unsigned short) ----------------
__device__ __forceinline__ unsigned short f2bf(float f) {
  unsigned int x = __builtin_bit_cast(unsigned int, f);
  x += 0x7fffu + ((x >> 16) & 1u);   // round-to-nearest-even
  return (unsigned short)(x >> 16);
}
__device__ __forceinline__ void unpack2(unsigned int w, float& lo, float& hi) {
  lo = __builtin_bit_cast(float, w << 16);
  hi = __builtin_bit_cast(float, w & 0xffff0000u);
}

// async global->LDS, 16B per lane; LDS dest = wave-uniform base + lane*16
typedef __attribute__((address_space(1))) const void gv_t;
typedef __attribute__((address_space(3))) void lv_t;
__device__ __forceinline__ void gll16(const void* g, void* l) {
  __builtin_amdgcn_global_load_lds((gv_t*)g, (lv_t*)l, 16, 0, 0);
}

// ---------------------------------------------------------------------------
// init + edge-index dtype probe (odd words of int64 src row are all zero)
// ---------------------------------------------------------------------------
__global__ __launch_bounds__(256) void k_init(int* __restrict__ deg,
                                              int* __restrict__ counter,
                                              int* __restrict__ flag) {
  int i = blockIdx.x * 256 + threadIdx.x;
  if (i < N_NODES) deg[i] = 0;
  if (i == 0) { *counter = 0; *flag = 0; }
}

__global__ __launch_bounds__(256) void k_detect(const int* __restrict__ ei,
                                                int* __restrict__ flag) {
  int i = blockIdx.x * 256 + threadIdx.x;
  bool nz = (i < N_EDGES) && (ei[2 * i + 1] != 0);
  if (__any(nz) && (threadIdx.x & 63) == 0) atomicOr(flag, 1);
}

__device__ __forceinline__ int edge_src(const int* ei, int f, int i) {
  return f ? ei[i] : ei[2 * i];
}
__device__ __forceinline__ int edge_dst(const int* ei, int f, int i) {
  return f ? ei[N_EDGES + i] : ei[2 * (N_EDGES + i)];
}

// ---------------------------------------------------------------------------
// CSR build grouped by dst (range order irrelevant -> atomic range alloc)
// ---------------------------------------------------------------------------
__global__ __launch_bounds__(256) void k_count(const int* __restrict__ ei,
                                               const int* __restrict__ flag,
                                               int* __restrict__ deg) {
  int i = blockIdx.x * 256 + threadIdx.x;
  if (i >= E_TOT) return;
  int f = *flag;
  int d = (i < N_EDGES) ? edge_dst(ei, f, i) : (i - N_EDGES);
  atomicAdd(deg + d, 1);
}

__global__ __launch_bounds__(256) void k_alloc(const int* __restrict__ deg,
                                               int* __restrict__ off,
                                               int* __restrict__ pos,
                                               int* __restrict__ counter) {
  int i = blockIdx.x * 256 + threadIdx.x;
  if (i >= N_NODES) return;
  int r = atomicAdd(counter, deg[i]);
  off[i] = r;
  pos[i] = r;
}

__global__ __launch_bounds__(256) void k_fill(const int* __restrict__ ei,
                                              const int* __restrict__ flag,
                                              int* __restrict__ pos,
                                              int* __restrict__ csr_src) {
  int i = blockIdx.x * 256 + threadIdx.x;
  if (i >= E_TOT) return;
  int f = *flag;
  int s, d;
  if (i < N_EDGES) { s = edge_src(ei, f, i); d = edge_dst(ei, f, i); }
  else             { s = d = i - N_EDGES; }
  int slot = atomicAdd(pos + d, 1);
  csr_src[slot] = s;
}

// ---------------------------------------------------------------------------
// conversion kernels (one-shot, tiny)
// x [N,182] f32 -> xb [*,192] bf16 (pad cols zeroed; tail rows untouched)
// ---------------------------------------------------------------------------
__global__ __launch_bounds__(256) void k_cvt_x(const float* __restrict__ x,
                                               unsigned short* __restrict__ xb) {
  int i = blockIdx.x * 256 + threadIdx.x;
  if (i >= N_NODES * K1P) return;
  int row = i / K1P, col = i - row * K1P;
  float v = (col < FIN) ? x[(size_t)row * FIN + col] : 0.f;
  xb[i] = f2bf(v);
}

// W [K,512] f32 -> Wt [512,Kpad] bf16 (transposed, pad k zeroed)
__global__ __launch_bounds__(256) void k_cvt_wt(const float* __restrict__ W,
                                                unsigned short* __restrict__ Wt,
                                                int K, int Kpad) {
  int i = blockIdx.x * 256 + threadIdx.x;
  if (i >= 512 * Kpad) return;
  int n = i / Kpad, k = i - n * Kpad;
  Wt[i] = f2bf(k < K ? W[(size_t)k * 512 + n] : 0.f);
}

// ---------------------------------------------------------------------------
// bf16 MFMA GEMM (m97 structure): C[M_PAD,512] = A[M_PAD,lda] @ Bt[512,lda]^T
// 128x128 tile, 4 waves (2x2), each wave 4x4 frags of 16x16x32, BK=32.
// A,Bt bf16; C bf16 (+bias+relu fp32 epilogue). No bounds checks: M,K,N
// padded by construction.
// ---------------------------------------------------------------------------
template<bool BIAS_RELU>
__global__ __launch_bounds__(256)
void gemm_mfma(const unsigned short* __restrict__ A,
               const unsigned short* __restrict__ Bt,
               const float* __restrict__ bias,
               unsigned short* __restrict__ C,
               int lda)
{
  __shared__ unsigned short As[128 * 32];   // [m][k] 8 KB
  __shared__ unsigned short Bs[128 * 32];   // [n][k] 8 KB
  const int t    = threadIdx.x;
  const int w    = t >> 6;
  const int lane = t & 63;
  const int r    = lane & 15;
  const int q    = lane >> 4;
  const int bm   = blockIdx.y * 128;
  const int bn   = blockIdx.x * 128;
  const int wm   = (w >> 1) * 64;
  const int wn   = (w & 1) * 64;

  // staging: 8 issues of 64 lanes x 16B cover each 8KB tile; wave w owns
  // issues w*2, w*2+1. chunk = issue*64+lane; row = chunk>>2, colgrp = chunk&3
  const int ch0 = (w * 2 + 0) * 64 + lane;
  const int ch1 = (w * 2 + 1) * 64 + lane;
  const unsigned short* gA0 = A + (size_t)(bm + (ch0 >> 2)) * lda + (ch0 & 3) * 8;
  const unsigned short* gA1 = A + (size_t)(bm + (ch1 >> 2)) * lda + (ch1 & 3) * 8;
  const unsigned short* gB0 = Bt + (size_t)(bn + (ch0 >> 2)) * lda + (ch0 & 3) * 8;
  const unsigned short* gB1 = Bt + (size_t)(bn + (ch1 >> 2)) * lda + (ch1 & 3) * 8;
  unsigned short* lA0 = As + (w * 2 + 0) * 512;   // 1024 B = 512 ushort
  unsigned short* lA1 = As + (w * 2 + 1) * 512;
  unsigned short* lB0 = Bs + (w * 2 + 0) * 512;
  unsigned short* lB1 = Bs + (w * 2 + 1) * 512;

  floatx4 acc[4][4] = {};

  for (int k0 = 0; k0 < lda; k0 += 32) {
    gll16(gA0 + k0, lA0);
    gll16(gA1 + k0, lA1);
    gll16(gB0 + k0, lB0);
    gll16(gB1 + k0, lB1);
    __syncthreads();   // vmcnt(0) drain + barrier

    short8 af[4], bfr[4];
#pragma unroll
    for (int im = 0; im < 4; ++im)
      af[im] = *(const short8*)(As + (wm + im * 16 + r) * 32 + q * 8);
#pragma unroll
    for (int in = 0; in < 4; ++in)
      bfr[in] = *(const short8*)(Bs + (wn + in * 16 + r) * 32 + q * 8);
#pragma unroll
    for (int im = 0; im < 4; ++im)
#pragma unroll
      for (int in = 0; in < 4; ++in)
        acc[im][in] = __builtin_amdgcn_mfma_f32_16x16x32_bf16(
            af[im], bfr[in], acc[im][in], 0, 0, 0);
    __syncthreads();
  }

  // epilogue: C/D layout col=lane&15, row=q*4+reg
#pragma unroll
  for (int in = 0; in < 4; ++in) {
    const int col = bn + wn + in * 16 + r;
    float bv = BIAS_RELU ? bias[col] : 0.f;
#pragma unroll
    for (int im = 0; im < 4; ++im) {
      const size_t rowbase = (size_t)(bm + wm + im * 16 + q * 4) * 512 + col;
#pragma unroll
      for (int rr = 0; rr < 4; ++rr) {
        float v = acc[im][in][rr];
        if (BIAS_RELU) v = fmaxf(v + bv, 0.f);
        C[rowbase + (size_t)rr * 512] = f2bf(v);
      }
    }
  }
}

// ---------------------------------------------------------------------------
// Per-node attention dots on bf16 h: s[n,h] = sum_c h[n,h*128+c]*a[h,c]
// ---------------------------------------------------------------------------
__global__ __launch_bounds__(256) void k_sdots(const unsigned short* __restrict__ h,
                                               const float* __restrict__ a_src,
                                               const float* __restrict__ a_dst,
                                               float* __restrict__ s_src,
                                               float* __restrict__ s_dst) {
  int node = blockIdx.x * 4 + (threadIdx.x >> 6);
  int lane = threadIdx.x & 63;
  if (node >= N_NODES) return;
  uint4 w = ((const uint4*)(h + (size_t)node * D))[lane];
  float v[8];
  unpack2(w.x, v[0], v[1]); unpack2(w.y, v[2], v[3]);
  unpack2(w.z, v[4], v[5]); unpack2(w.w, v[6], v[7]);
  const float4* as = (const float4*)a_src;
  const float4* ad = (const float4*)a_dst;
  float4 s0 = as[lane*2], s1 = as[lane*2+1];
  float4 d0 = ad[lane*2], d1 = ad[lane*2+1];
  float ps = v[0]*s0.x + v[1]*s0.y + v[2]*s0.z + v[3]*s0.w
           + v[4]*s1.x + v[5]*s1.y + v[6]*s1.z + v[7]*s1.w;
  float pd = v[0]*d0.x + v[1]*d0.y + v[2]*d0.z + v[3]*d0.w
           + v[4]*d1.x + v[5]*d1.y + v[6]*d1.z + v[7]*d1.w;
#pragma unroll
  for (int o = 1; o < 16; o <<= 1) {
    ps += __shfl_xor(ps, o);
    pd += __shfl_xor(pd, o);
  }
  if ((lane & 15) == 0) {
    int hh = lane >> 4;
    s_src[node*4 + hh] = ps;
    s_dst[node*4 + hh] = pd;
  }
}

// ---------------------------------------------------------------------------
// Fused segment-softmax + weighted aggregation + bias + LayerNorm + ELU.
// One wave per dst node; alpha recomputed inline (never materialized).
// ---------------------------------------------------------------------------
__global__ __launch_bounds__(256) void k_aggregate(const unsigned short* __restrict__ h,
                                                   const int* __restrict__ csr_src,
                                                   const int* __restrict__ off,
                                                   const int* __restrict__ deg,
                                                   const float* __restrict__ s_src,
                                                   const float* __restrict__ s_dst,
                                                   const float* __restrict__ bvec,
                                                   const float* __restrict__ gvec,
                                                   const float* __restrict__ bevec,
                                                   unsigned short* __restrict__ out) {
  int node = blockIdx.x * 4 + (threadIdx.x >> 6);
  int lane = threadIdx.x & 63;
  if (node >= N_NODES) return;
  int o = off[node], cnt = deg[node];
  int total = cnt * 4;
  int hh = lane & 3;
  float sd = s_dst[(size_t)node*4 + hh];

  float m = -1e30f;
  for (int idx = lane; idx < total; idx += 64) {
    int s = csr_src[o + (idx >> 2)];
    float e = s_src[(size_t)s*4 + hh] + sd;
    e = (e > 0.f) ? e : NEG_SLOPE * e;
    m = fmaxf(m, e);
  }
#pragma unroll
  for (int o2 = 4; o2 < 64; o2 <<= 1) m = fmaxf(m, __shfl_xor(m, o2));

  float sum = 0.f;
  for (int idx = lane; idx < total; idx += 64) {
    int s = csr_src[o + (idx >> 2)];
    float e = s_src[(size_t)s*4 + hh] + sd;
    e = (e > 0.f) ? e : NEG_SLOPE * e;
    sum += expf(e - m);
  }
#pragma unroll
  for (int o2 = 4; o2 < 64; o2 <<= 1) sum += __shfl_xor(sum, o2);

  int head = lane >> 4;
  float mH   = __shfl(m, head);
  float invH = 1.f / __shfl(sum, head);
  float sdH  = s_dst[(size_t)node*4 + head];

  float acc[8] = {0.f,0.f,0.f,0.f,0.f,0.f,0.f,0.f};
  for (int j = 0; j < cnt; ++j) {
    int s = csr_src[o + j];
    float e = s_src[(size_t)s*4 + head] + sdH;
    e = (e > 0.f) ? e : NEG_SLOPE * e;
    float p = expf(e - mH) * invH;
    uint4 w = ((const uint4*)(h + (size_t)s * D))[lane];
    float v[8];
    unpack2(w.x, v[0], v[1]); unpack2(w.y, v[2], v[3]);
    unpack2(w.z, v[4], v[5]); unpack2(w.w, v[6], v[7]);
#pragma unroll
    for (int k = 0; k < 8; ++k) acc[k] += p * v[k];
  }

  const float4* bb = (const float4*)bvec;
  float4 b0 = bb[lane*2], b1 = bb[lane*2+1];
  float bl[8] = {b0.x,b0.y,b0.z,b0.w,b1.x,b1.y,b1.z,b1.w};
#pragma unroll
  for (int k = 0; k < 8; ++k) acc[k] += bl[k];

  float ps = 0.f, pq = 0.f;
#pragma unroll
  for (int k = 0; k < 8; ++k) { ps += acc[k]; pq += acc[k]*acc[k]; }
#pragma unroll
  for (int o2 = 1; o2 < 64; o2 <<= 1) {
    ps += __shfl_xor(ps, o2);
    pq += __shfl_xor(pq, o2);
  }
  float mu  = ps * (1.f/512.f);
  float var = pq * (1.f/512.f) - mu*mu;
  float rstd = rsqrtf(var + LN_EPS);

  const float4* gg = (const float4*)gvec;
  const float4* ee = (const float4*)bevec;
  float4 g0 = gg[lane*2], g1 = gg[lane*2+1];
  float4 e0 = ee[lane*2], e1 = ee[lane*2+1];
  float gs[8] = {g0.x,g0.y,g0.z,g0.w,g1.x,g1.y,g1.z,g1.w};
  float es[8] = {e0.x,e0.y,e0.z,e0.w,e1.x,e1.y,e1.z,e1.w};

  unsigned short us[8];
#pragma unroll
  for (int k = 0; k < 8; ++k) {
    float y = (acc[k] - mu) * rstd * gs[k] + es[k];
    y = (y > 0.f) ? y : expm1f(y);
    us[k] = f2bf(y);
  }
  uint4 w;
  w.x = (unsigned int)us[0] | ((unsigned int)us[1] << 16);
  w.y = (unsigned int)us[2] | ((unsigned int)us[3] << 16);
  w.z = (unsigned int)us[4] | ((unsigned int)us[5] << 16);
  w.w = (unsigned int)us[6] | ((unsigned int)us[7] << 16);
  ((uint4*)(out + (size_t)node * D))[lane] = w;
}

// ---------------------------------------------------------------------------
// Final projection: out[n,0:2] = z[n,:] @ Wc2[512,2] + bc2 (z is bf16)
// ---------------------------------------------------------------------------
__global__ __launch_bounds__(256) void k_final(const unsigned short* __restrict__ z,
                                               const float* __restrict__ Wc2,
                                               const float* __restrict__ bc2,
                                               float* __restrict__ out) {
  int node = blockIdx.x * 4 + (threadIdx.x >> 6);
  int lane = threadIdx.x & 63;
  if (node >= N_NODES) return;
  uint4 w = ((const uint4*)(z + (size_t)node * D))[lane];
  float zv[8];
  unpack2(w.x, zv[0], zv[1]); unpack2(w.y, zv[2], zv[3]);
  unpack2(w.z, zv[4], zv[5]); unpack2(w.w, zv[6], zv[7]);
  const float* wr = Wc2 + (size_t)lane * 16;
  float a0 = 0.f, a1 = 0.f;
#pragma unroll
  for (int k = 0; k < 8; ++k) {
    a0 += zv[k] * wr[k*2];
    a1 += zv[k] * wr[k*2+1];
  }
#pragma unroll
  for (int o2 = 1; o2 < 64; o2 <<= 1) {
    a0 += __shfl_xor(a0, o2);
    a1 += __shfl_xor(a1, o2);
  }
  if (lane == 0) {
    out[(size_t)node*2]     = a0 + bc2[0];
    out[(size_t)node*2 + 1] = a1 + bc2[1];
  }
}

// ---------------------------------------------------------------------------
extern "C" void kernel_launch(void* const* d_in, const int* in_sizes, int n_in,
                              void* d_out, int out_size, void* d_ws, size_t ws_size,
                              hipStream_t stream) {
  const float* x      = (const float*)d_in[0];
  const int*   ei     = (const int*)  d_in[1];
  const float* W1     = (const float*)d_in[2];
  const float* a_src1 = (const float*)d_in[3];
  const float* a_dst1 = (const float*)d_in[4];
  const float* b1     = (const float*)d_in[5];
  const float* g1     = (const float*)d_in[6];
  const float* be1    = (const float*)d_in[7];
  const float* W2     = (const float*)d_in[8];
  const float* a_src2 = (const float*)d_in[9];
  const float* a_dst2 = (const float*)d_in[10];
  const float* b2     = (const float*)d_in[11];
  const float* g2     = (const float*)d_in[12];
  const float* be2    = (const float*)d_in[13];
  const float* Wc1    = (const float*)d_in[14];
  const float* bc1    = (const float*)d_in[15];
  const float* Wc2    = (const float*)d_in[16];
  const float* bc2    = (const float*)d_in[17];
  float* outp = (float*)d_out;

  char* p = (char*)d_ws;
  auto alloc = [&](size_t bytes) {
    char* r = p;
    p += (bytes + 255) & ~(size_t)255;
    return r;
  };
  unsigned short* hbuf = (unsigned short*)alloc((size_t)M_PAD * D * 2); // 102.5 MB
  unsigned short* obuf = (unsigned short*)alloc((size_t)M_PAD * D * 2); // 102.5 MB
  unsigned short* w1t  = (unsigned short*)alloc((size_t)512 * K1P * 2);
  unsigned short* w2t  = (unsigned short*)alloc((size_t)512 * 512 * 2);
  unsigned short* wc1t = (unsigned short*)alloc((size_t)512 * 512 * 2);
  int*   csr_src = (int*)  alloc((size_t)E_TOT * 4);                    // 6.8 MB
  int*   deg     = (int*)  alloc((size_t)N_NODES * 4);
  int*   off     = (int*)  alloc((size_t)N_NODES * 4);
  int*   pos     = (int*)  alloc((size_t)N_NODES * 4);
  int*   counter = (int*)  alloc(256);
  int*   flag    = (int*)  alloc(256);
  float* s_src   = (float*)alloc((size_t)N_NODES * 4 * 4);
  float* s_dst   = (float*)alloc((size_t)N_NODES * 4 * 4);
  // xb aliases obuf's first 38.4 MB (dead after GEMM-1, then overwritten)
  unsigned short* xb = obuf;

  const int EB = (E_TOT + 255) / 256;
  const int NB = (N_NODES + 255) / 256;
  const int DB = (N_EDGES + 255) / 256;
  const int NW = (N_NODES + 3) / 4;
  dim3 gg(4, M_PAD / 128);   // N=512 -> 4 col-blocks, 782 row-blocks

  // init + dtype probe + CSR build + weight conversion
  k_init  <<<NB, 256, 0, stream>>>(deg, counter, flag);
  k_detect<<<DB, 256, 0, stream>>>(ei, flag);
  k_count <<<EB, 256, 0, stream>>>(ei, flag, deg);
  k_alloc <<<NB, 256, 0, stream>>>(deg, off, pos, counter);
  k_fill  <<<EB, 256, 0, stream>>>(ei, flag, pos, csr_src);

  k_cvt_x <<<(N_NODES * K1P + 255) / 256, 256, 0, stream>>>(x, xb);
  k_cvt_wt<<<(512 * K1P + 255) / 256, 256, 0, stream>>>(W1, w1t, FIN, K1P);
  k_cvt_wt<<<(512 * 512 + 255) / 256, 256, 0, stream>>>(W2, w2t, 512, 512);
  k_cvt_wt<<<(512 * 512 + 255) / 256, 256, 0, stream>>>(Wc1, wc1t, 512, 512);

  // Layer 1
  gemm_mfma<false><<<gg, 256, 0, stream>>>(xb, w1t, nullptr, hbuf, K1P);
  k_sdots    <<<NW, 256, 0, stream>>>(hbuf, a_src1, a_dst1, s_src, s_dst);
  k_aggregate<<<NW, 256, 0, stream>>>(hbuf, csr_src, off, deg, s_src, s_dst, b1, g1, be1, obuf);

  // Layer 2
  gemm_mfma<false><<<gg, 256, 0, stream>>>(obuf, w2t, nullptr, hbuf, 512);
  k_sdots    <<<NW, 256, 0, stream>>>(hbuf, a_src2, a_dst2, s_src, s_dst);
  k_aggregate<<<NW, 256, 0, stream>>>(hbuf, csr_src, off, deg, s_src, s_dst, b2, g2, be2, obuf);

  // Classifier
  gemm_mfma<true><<<gg, 256, 0, stream>>>(obuf, wc1t, bc1, hbuf, 512);
  k_final    <<<NW, 256, 0, stream>>>(hbuf, Wc2, bc2, outp);
}

// Round 4
// 1486.732 us; speedup vs baseline: 2.6880x; 1.0334x over previous
//
#include <hip/hip_runtime.h>
#include <math.h>

static constexpr int N_NODES = 100000;
static constexpr int N_EDGES = 1600000;
static constexpr int E_TOT   = N_NODES + N_EDGES;   // edges + self-loops
static constexpr int D   = 512;
static constexpr int FIN = 182;
static constexpr int K1P = 192;                     // FIN padded to mult of 32
static constexpr int M_PAD = 100096;                // 782 * 128
static constexpr float NEG_SLOPE = 0.2f;
static constexpr float LN_EPS = 1e-5f;

typedef __attribute__((ext_vector_type(8))) short short8;
typedef __attribute__((ext_vector_type(4))) float floatx4;

// ---------------- bf16 helpers (storage type: unsigned short) ----------------
__device__ __forceinline__ unsigned short f2bf(float f) {
  unsigned int x = __builtin_bit_cast(unsigned int, f);
  x += 0x7fffu + ((x >> 16) & 1u);   // round-to-nearest-even
  return (unsigned short)(x >> 16);
}
__device__ __forceinline__ void unpack2(unsigned int w, float& lo, float& hi) {
  lo = __builtin_bit_cast(float, w << 16);
  hi = __builtin_bit_cast(float, w & 0xffff0000u);
}

// async global->LDS, 16B per lane; LDS dest = wave-uniform base + lane*16
typedef __attribute__((address_space(1))) const void gv_t;
typedef __attribute__((address_space(3))) void lv_t;
__device__ __forceinline__ void gll16(const void* g, void* l) {
  __builtin_amdgcn_global_load_lds((gv_t*)g, (lv_t*)l, 16, 0, 0);
}

// ---------------------------------------------------------------------------
// init + edge-index dtype probe (odd words of int64 src row are all zero)
// ---------------------------------------------------------------------------
__global__ __launch_bounds__(256) void k_init(int* __restrict__ deg,
                                              int* __restrict__ counter,
                                              int* __restrict__ flag) {
  int i = blockIdx.x * 256 + threadIdx.x;
  if (i < N_NODES) deg[i] = 0;
  if (i == 0) { *counter = 0; *flag = 0; }
}

__global__ __launch_bounds__(256) void k_detect(const int* __restrict__ ei,
                                                int* __restrict__ flag) {
  int i = blockIdx.x * 256 + threadIdx.x;
  bool nz = (i < N_EDGES) && (ei[2 * i + 1] != 0);
  if (__any(nz) && (threadIdx.x & 63) == 0) atomicOr(flag, 1);
}

__device__ __forceinline__ int edge_src(const int* ei, int f, int i) {
  return f ? ei[i] : ei[2 * i];
}
__device__ __forceinline__ int edge_dst(const int* ei, int f, int i) {
  return f ? ei[N_EDGES + i] : ei[2 * (N_EDGES + i)];
}

// ---------------------------------------------------------------------------
// CSR build grouped by dst (range order irrelevant -> atomic range alloc)
// ---------------------------------------------------------------------------
__global__ __launch_bounds__(256) void k_count(const int* __restrict__ ei,
                                               const int* __restrict__ flag,
                                               int* __restrict__ deg) {
  int i = blockIdx.x * 256 + threadIdx.x;
  if (i >= E_TOT) return;
  int f = *flag;
  int d = (i < N_EDGES) ? edge_dst(ei, f, i) : (i - N_EDGES);
  atomicAdd(deg + d, 1);
}

__global__ __launch_bounds__(256) void k_alloc(const int* __restrict__ deg,
                                               int* __restrict__ off,
                                               int* __restrict__ pos,
                                               int* __restrict__ counter) {
  int i = blockIdx.x * 256 + threadIdx.x;
  if (i >= N_NODES) return;
  int r = atomicAdd(counter, deg[i]);
  off[i] = r;
  pos[i] = r;
}

__global__ __launch_bounds__(256) void k_fill(const int* __restrict__ ei,
                                              const int* __restrict__ flag,
                                              int* __restrict__ pos,
                                              int* __restrict__ csr_src) {
  int i = blockIdx.x * 256 + threadIdx.x;
  if (i >= E_TOT) return;
  int f = *flag;
  int s, d;
  if (i < N_EDGES) { s = edge_src(ei, f, i); d = edge_dst(ei, f, i); }
  else             { s = d = i - N_EDGES; }
  int slot = atomicAdd(pos + d, 1);
  csr_src[slot] = s;
}

// ---------------------------------------------------------------------------
// conversion kernels (one-shot, tiny)
// ---------------------------------------------------------------------------
__global__ __launch_bounds__(256) void k_cvt_x(const float* __restrict__ x,
                                               unsigned short* __restrict__ xb) {
  int i = blockIdx.x * 256 + threadIdx.x;
  if (i >= N_NODES * K1P) return;
  int row = i / K1P, col = i - row * K1P;
  float v = (col < FIN) ? x[(size_t)row * FIN + col] : 0.f;
  xb[i] = f2bf(v);
}

__global__ __launch_bounds__(256) void k_cvt_wt(const float* __restrict__ W,
                                                unsigned short* __restrict__ Wt,
                                                int K, int Kpad) {
  int i = blockIdx.x * 256 + threadIdx.x;
  if (i >= 512 * Kpad) return;
  int n = i / Kpad, k = i - n * Kpad;
  Wt[i] = f2bf(k < K ? W[(size_t)k * 512 + n] : 0.f);
}

// ---------------------------------------------------------------------------
// bf16 MFMA GEMM (m97 structure): C[M_PAD,512] = A[M_PAD,lda] @ Bt[512,lda]^T
// ---------------------------------------------------------------------------
template<bool BIAS_RELU>
__global__ __launch_bounds__(256)
void gemm_mfma(const unsigned short* __restrict__ A,
               const unsigned short* __restrict__ Bt,
               const float* __restrict__ bias,
               unsigned short* __restrict__ C,
               int lda)
{
  __shared__ unsigned short As[128 * 32];   // [m][k] 8 KB
  __shared__ unsigned short Bs[128 * 32];   // [n][k] 8 KB
  const int t    = threadIdx.x;
  const int w    = t >> 6;
  const int lane = t & 63;
  const int r    = lane & 15;
  const int q    = lane >> 4;
  const int bm   = blockIdx.y * 128;
  const int bn   = blockIdx.x * 128;
  const int wm   = (w >> 1) * 64;
  const int wn   = (w & 1) * 64;

  const int ch0 = (w * 2 + 0) * 64 + lane;
  const int ch1 = (w * 2 + 1) * 64 + lane;
  const unsigned short* gA0 = A + (size_t)(bm + (ch0 >> 2)) * lda + (ch0 & 3) * 8;
  const unsigned short* gA1 = A + (size_t)(bm + (ch1 >> 2)) * lda + (ch1 & 3) * 8;
  const unsigned short* gB0 = Bt + (size_t)(bn + (ch0 >> 2)) * lda + (ch0 & 3) * 8;
  const unsigned short* gB1 = Bt + (size_t)(bn + (ch1 >> 2)) * lda + (ch1 & 3) * 8;
  unsigned short* lA0 = As + (w * 2 + 0) * 512;
  unsigned short* lA1 = As + (w * 2 + 1) * 512;
  unsigned short* lB0 = Bs + (w * 2 + 0) * 512;
  unsigned short* lB1 = Bs + (w * 2 + 1) * 512;

  floatx4 acc[4][4] = {};

  for (int k0 = 0; k0 < lda; k0 += 32) {
    gll16(gA0 + k0, lA0);
    gll16(gA1 + k0, lA1);
    gll16(gB0 + k0, lB0);
    gll16(gB1 + k0, lB1);
    __syncthreads();

    short8 af[4], bfr[4];
#pragma unroll
    for (int im = 0; im < 4; ++im)
      af[im] = *(const short8*)(As + (wm + im * 16 + r) * 32 + q * 8);
#pragma unroll
    for (int in = 0; in < 4; ++in)
      bfr[in] = *(const short8*)(Bs + (wn + in * 16 + r) * 32 + q * 8);
#pragma unroll
    for (int im = 0; im < 4; ++im)
#pragma unroll
      for (int in = 0; in < 4; ++in)
        acc[im][in] = __builtin_amdgcn_mfma_f32_16x16x32_bf16(
            af[im], bfr[in], acc[im][in], 0, 0, 0);
    __syncthreads();
  }

  // epilogue: C/D layout col=lane&15, row=q*4+reg
#pragma unroll
  for (int in = 0; in < 4; ++in) {
    const int col = bn + wn + in * 16 + r;
    float bv = BIAS_RELU ? bias[col] : 0.f;
#pragma unroll
    for (int im = 0; im < 4; ++im) {
      const size_t rowbase = (size_t)(bm + wm + im * 16 + q * 4) * 512 + col;
#pragma unroll
      for (int rr = 0; rr < 4; ++rr) {
        float v = acc[im][in][rr];
        if (BIAS_RELU) v = fmaxf(v + bv, 0.f);
        C[rowbase + (size_t)rr * 512] = f2bf(v);
      }
    }
  }
}

// ---------------------------------------------------------------------------
// Per-node attention dots on bf16 h: s[n,h] = sum_c h[n,h*128+c]*a[h,c]
// ---------------------------------------------------------------------------
__global__ __launch_bounds__(256) void k_sdots(const unsigned short* __restrict__ h,
                                               const float* __restrict__ a_src,
                                               const float* __restrict__ a_dst,
                                               float* __restrict__ s_src,
                                               float* __restrict__ s_dst) {
  int node = blockIdx.x * 4 + (threadIdx.x >> 6);
  int lane = threadIdx.x & 63;
  if (node >= N_NODES) return;
  uint4 w = ((const uint4*)(h + (size_t)node * D))[lane];
  float v[8];
  unpack2(w.x, v[0], v[1]); unpack2(w.y, v[2], v[3]);
  unpack2(w.z, v[4], v[5]); unpack2(w.w, v[6], v[7]);
  const float4* as = (const float4*)a_src;
  const float4* ad = (const float4*)a_dst;
  float4 s0 = as[lane*2], s1 = as[lane*2+1];
  float4 d0 = ad[lane*2], d1 = ad[lane*2+1];
  float ps = v[0]*s0.x + v[1]*s0.y + v[2]*s0.z + v[3]*s0.w
           + v[4]*s1.x + v[5]*s1.y + v[6]*s1.z + v[7]*s1.w;
  float pd = v[0]*d0.x + v[1]*d0.y + v[2]*d0.z + v[3]*d0.w
           + v[4]*d1.x + v[5]*d1.y + v[6]*d1.z + v[7]*d1.w;
#pragma unroll
  for (int o = 1; o < 16; o <<= 1) {
    ps += __shfl_xor(ps, o);
    pd += __shfl_xor(pd, o);
  }
  if ((lane & 15) == 0) {
    int hh = lane >> 4;
    s_src[node*4 + hh] = ps;
    s_dst[node*4 + hh] = pd;
  }
}

// ---------------------------------------------------------------------------
// Fused segment-softmax + aggregation + bias + LayerNorm + ELU, SINGLE PASS.
// Softmax without max-shift (|e| <~ 10, fp32-safe; shift-invariant math):
//   out = (sum_j exp(e_j) * h[src_j]) / (sum_j exp(e_j))
// One wave per dst node. Edge index + row base forced wave-uniform (SGPR)
// via readfirstlane; row gather software-pipelined one edge ahead.
// ---------------------------------------------------------------------------
__global__ __launch_bounds__(256) void k_aggregate(const unsigned short* __restrict__ h,
                                                   const int* __restrict__ csr_src,
                                                   const int* __restrict__ off,
                                                   const int* __restrict__ deg,
                                                   const float* __restrict__ s_src,
                                                   const float* __restrict__ s_dst,
                                                   const float* __restrict__ bvec,
                                                   const float* __restrict__ gvec,
                                                   const float* __restrict__ bevec,
                                                   unsigned short* __restrict__ out) {
  int node = blockIdx.x * 4 + (threadIdx.x >> 6);
  int lane = threadIdx.x & 63;
  if (node >= N_NODES) return;
  const int o   = __builtin_amdgcn_readfirstlane(off[node]);
  const int cnt = __builtin_amdgcn_readfirstlane(deg[node]);
  const int head = lane >> 4;
  const float sdH = s_dst[(size_t)node * 4 + head];

  float acc[8] = {0.f,0.f,0.f,0.f,0.f,0.f,0.f,0.f};
  float sum = 0.f;

  // pipeline: row j in flight while scoring/accumulating row j-1
  int s_cur = __builtin_amdgcn_readfirstlane(csr_src[o]);
  uint4 w_cur = ((const uint4*)(h + (size_t)s_cur * D))[lane];

  for (int j = 0; j < cnt; ++j) {
    int jn = (j + 1 < cnt) ? (j + 1) : j;
    int s_nxt = __builtin_amdgcn_readfirstlane(csr_src[o + jn]);
    uint4 w_nxt = ((const uint4*)(h + (size_t)s_nxt * D))[lane];

    float e = s_src[(size_t)s_cur * 4 + head] + sdH;
    e = (e > 0.f) ? e : NEG_SLOPE * e;
    float p = __expf(e);
    sum += p;
    float v[8];
    unpack2(w_cur.x, v[0], v[1]); unpack2(w_cur.y, v[2], v[3]);
    unpack2(w_cur.z, v[4], v[5]); unpack2(w_cur.w, v[6], v[7]);
#pragma unroll
    for (int k = 0; k < 8; ++k) acc[k] += p * v[k];

    s_cur = s_nxt;
    w_cur = w_nxt;
  }

  const float inv = 1.f / sum;
  const float4* bb = (const float4*)bvec;
  float4 b0 = bb[lane*2], b1 = bb[lane*2+1];
  float bl[8] = {b0.x,b0.y,b0.z,b0.w,b1.x,b1.y,b1.z,b1.w};
#pragma unroll
  for (int k = 0; k < 8; ++k) acc[k] = acc[k] * inv + bl[k];

  float ps = 0.f, pq = 0.f;
#pragma unroll
  for (int k = 0; k < 8; ++k) { ps += acc[k]; pq += acc[k]*acc[k]; }
#pragma unroll
  for (int o2 = 1; o2 < 64; o2 <<= 1) {
    ps += __shfl_xor(ps, o2);
    pq += __shfl_xor(pq, o2);
  }
  float mu  = ps * (1.f/512.f);
  float var = pq * (1.f/512.f) - mu*mu;
  float rstd = rsqrtf(var + LN_EPS);

  const float4* gg = (const float4*)gvec;
  const float4* ee = (const float4*)bevec;
  float4 g0 = gg[lane*2], g1 = gg[lane*2+1];
  float4 e0 = ee[lane*2], e1 = ee[lane*2+1];
  float gs[8] = {g0.x,g0.y,g0.z,g0.w,g1.x,g1.y,g1.z,g1.w};
  float es[8] = {e0.x,e0.y,e0.z,e0.w,e1.x,e1.y,e1.z,e1.w};

  unsigned short us[8];
#pragma unroll
  for (int k = 0; k < 8; ++k) {
    float y = (acc[k] - mu) * rstd * gs[k] + es[k];
    y = (y > 0.f) ? y : expm1f(y);
    us[k] = f2bf(y);
  }
  uint4 w;
  w.x = (unsigned int)us[0] | ((unsigned int)us[1] << 16);
  w.y = (unsigned int)us[2] | ((unsigned int)us[3] << 16);
  w.z = (unsigned int)us[4] | ((unsigned int)us[5] << 16);
  w.w = (unsigned int)us[6] | ((unsigned int)us[7] << 16);
  ((uint4*)(out + (size_t)node * D))[lane] = w;
}

// ---------------------------------------------------------------------------
// Final projection: out[n,0:2] = z[n,:] @ Wc2[512,2] + bc2 (z is bf16)
// ---------------------------------------------------------------------------
__global__ __launch_bounds__(256) void k_final(const unsigned short* __restrict__ z,
                                               const float* __restrict__ Wc2,
                                               const float* __restrict__ bc2,
                                               float* __restrict__ out) {
  int node = blockIdx.x * 4 + (threadIdx.x >> 6);
  int lane = threadIdx.x & 63;
  if (node >= N_NODES) return;
  uint4 w = ((const uint4*)(z + (size_t)node * D))[lane];
  float zv[8];
  unpack2(w.x, zv[0], zv[1]); unpack2(w.y, zv[2], zv[3]);
  unpack2(w.z, zv[4], zv[5]); unpack2(w.w, zv[6], zv[7]);
  const float* wr = Wc2 + (size_t)lane * 16;
  float a0 = 0.f, a1 = 0.f;
#pragma unroll
  for (int k = 0; k < 8; ++k) {
    a0 += zv[k] * wr[k*2];
    a1 += zv[k] * wr[k*2+1];
  }
#pragma unroll
  for (int o2 = 1; o2 < 64; o2 <<= 1) {
    a0 += __shfl_xor(a0, o2);
    a1 += __shfl_xor(a1, o2);
  }
  if (lane == 0) {
    out[(size_t)node*2]     = a0 + bc2[0];
    out[(size_t)node*2 + 1] = a1 + bc2[1];
  }
}

// ---------------------------------------------------------------------------
extern "C" void kernel_launch(void* const* d_in, const int* in_sizes, int n_in,
                              void* d_out, int out_size, void* d_ws, size_t ws_size,
                              hipStream_t stream) {
  const float* x      = (const float*)d_in[0];
  const int*   ei     = (const int*)  d_in[1];
  const float* W1     = (const float*)d_in[2];
  const float* a_src1 = (const float*)d_in[3];
  const float* a_dst1 = (const float*)d_in[4];
  const float* b1     = (const float*)d_in[5];
  const float* g1     = (const float*)d_in[6];
  const float* be1    = (const float*)d_in[7];
  const float* W2     = (const float*)d_in[8];
  const float* a_src2 = (const float*)d_in[9];
  const float* a_dst2 = (const float*)d_in[10];
  const float* b2     = (const float*)d_in[11];
  const float* g2     = (const float*)d_in[12];
  const float* be2    = (const float*)d_in[13];
  const float* Wc1    = (const float*)d_in[14];
  const float* bc1    = (const float*)d_in[15];
  const float* Wc2    = (const float*)d_in[16];
  const float* bc2    = (const float*)d_in[17];
  float* outp = (float*)d_out;

  char* p = (char*)d_ws;
  auto alloc = [&](size_t bytes) {
    char* r = p;
    p += (bytes + 255) & ~(size_t)255;
    return r;
  };
  unsigned short* hbuf = (unsigned short*)alloc((size_t)M_PAD * D * 2); // 102.5 MB
  unsigned short* obuf = (unsigned short*)alloc((size_t)M_PAD * D * 2); // 102.5 MB
  unsigned short* w1t  = (unsigned short*)alloc((size_t)512 * K1P * 2);
  unsigned short* w2t  = (unsigned short*)alloc((size_t)512 * 512 * 2);
  unsigned short* wc1t = (unsigned short*)alloc((size_t)512 * 512 * 2);
  int*   csr_src = (int*)  alloc((size_t)E_TOT * 4);                    // 6.8 MB
  int*   deg     = (int*)  alloc((size_t)N_NODES * 4);
  int*   off     = (int*)  alloc((size_t)N_NODES * 4);
  int*   pos     = (int*)  alloc((size_t)N_NODES * 4);
  int*   counter = (int*)  alloc(256);
  int*   flag    = (int*)  alloc(256);
  float* s_src   = (float*)alloc((size_t)N_NODES * 4 * 4);
  float* s_dst   = (float*)alloc((size_t)N_NODES * 4 * 4);
  // xb aliases obuf's first 38.4 MB (dead after GEMM-1, then overwritten)
  unsigned short* xb = obuf;

  const int EB = (E_TOT + 255) / 256;
  const int NB = (N_NODES + 255) / 256;
  const int DB = (N_EDGES + 255) / 256;
  const int NW = (N_NODES + 3) / 4;
  dim3 gg(4, M_PAD / 128);

  // init + dtype probe + CSR build + weight conversion
  k_init  <<<NB, 256, 0, stream>>>(deg, counter, flag);
  k_detect<<<DB, 256, 0, stream>>>(ei, flag);
  k_count <<<EB, 256, 0, stream>>>(ei, flag, deg);
  k_alloc <<<NB, 256, 0, stream>>>(deg, off, pos, counter);
  k_fill  <<<EB, 256, 0, stream>>>(ei, flag, pos, csr_src);

  k_cvt_x <<<(N_NODES * K1P + 255) / 256, 256, 0, stream>>>(x, xb);
  k_cvt_wt<<<(512 * K1P + 255) / 256, 256, 0, stream>>>(W1, w1t, FIN, K1P);
  k_cvt_wt<<<(512 * 512 + 255) / 256, 256, 0, stream>>>(W2, w2t, 512, 512);
  k_cvt_wt<<<(512 * 512 + 255) / 256, 256, 0, stream>>>(Wc1, wc1t, 512, 512);

  // Layer 1
  gemm_mfma<false><<<gg, 256, 0, stream>>>(xb, w1t, nullptr, hbuf, K1P);
  k_sdots    <<<NW, 256, 0, stream>>>(hbuf, a_src1, a_dst1, s_src, s_dst);
  k_aggregate<<<NW, 256, 0, stream>>>(hbuf, csr_src, off, deg, s_src, s_dst, b1, g1, be1, obuf);

  // Layer 2
  gemm_mfma<false><<<gg, 256, 0, stream>>>(obuf, w2t, nullptr, hbuf, 512);
  k_sdots    <<<NW, 256, 0, stream>>>(hbuf, a_src2, a_dst2, s_src, s_dst);
  k_aggregate<<<NW, 256, 0, stream>>>(hbuf, csr_src, off, deg, s_src, s_dst, b2, g2, be2, obuf);

  // Classifier
  gemm_mfma<true><<<gg, 256, 0, stream>>>(obuf, wc1t, bc1, hbuf, 512);
  k_final    <<<NW, 256, 0, stream>>>(hbuf, Wc2, bc2, outp);
}

// Round 5
// 1198.798 us; speedup vs baseline: 3.3336x; 1.2402x over previous
//
#include <hip/hip_runtime.h>
#include <math.h>

static constexpr int N_NODES = 100000;
static constexpr int N_EDGES = 1600000;
static constexpr int E_TOT   = N_NODES + N_EDGES;   // edges + self-loops
static constexpr int D   = 512;
static constexpr int FIN = 182;
static constexpr int K1P = 192;                     // FIN padded to mult of 32
static constexpr int M_PAD = 100096;                // 782 * 128
static constexpr float NEG_SLOPE = 0.2f;
static constexpr float LN_EPS = 1e-5f;

typedef __attribute__((ext_vector_type(8))) short short8;
typedef __attribute__((ext_vector_type(4))) float floatx4;

// ---------------- bf16 helpers (storage type: unsigned short) ----------------
__device__ __forceinline__ unsigned short f2bf(float f) {
  unsigned int x = __builtin_bit_cast(unsigned int, f);
  x += 0x7fffu + ((x >> 16) & 1u);   // round-to-nearest-even
  return (unsigned short)(x >> 16);
}
__device__ __forceinline__ void unpack2(unsigned int w, float& lo, float& hi) {
  lo = __builtin_bit_cast(float, w << 16);
  hi = __builtin_bit_cast(float, w & 0xffff0000u);
}

// async global->LDS, 16B per lane; LDS dest = wave-uniform base + lane*16
typedef __attribute__((address_space(1))) const void gv_t;
typedef __attribute__((address_space(3))) void lv_t;
__device__ __forceinline__ void gll16(const void* g, void* l) {
  __builtin_amdgcn_global_load_lds((gv_t*)g, (lv_t*)l, 16, 0, 0);
}

// ---------------------------------------------------------------------------
// init + edge-index dtype probe.
// Single workgroup samples 2048 odd 32-bit words of the src row: all-zero
// <=> int64 storage (P[false verdict | int32] ~ (1e-5)^2048 ~ 0). One plain
// store, no atomic storm (previous version: 26.5k same-address atomicOr
// = 286 us of serialized L2 atomics).
// ---------------------------------------------------------------------------
__global__ __launch_bounds__(256) void k_init(int* __restrict__ deg,
                                              int* __restrict__ counter,
                                              int* __restrict__ flag) {
  int i = blockIdx.x * 256 + threadIdx.x;
  if (i < N_NODES) deg[i] = 0;
  if (i == 0) { *counter = 0; *flag = 0; }
}

__global__ __launch_bounds__(256) void k_detect(const int* __restrict__ ei,
                                                int* __restrict__ flag) {
  bool nz = false;
#pragma unroll
  for (int r = 0; r < 8; ++r) {
    int i = threadIdx.x + r * 256;          // sample edges 0..2047
    nz |= (ei[2 * i + 1] != 0);
  }
  // block-wide OR via two ballots through LDS-free path: wave ballot + lane0
  __shared__ int sh[4];
  int wv = threadIdx.x >> 6;
  if ((threadIdx.x & 63) == 0) sh[wv] = 0;
  __syncthreads();
  if (__any(nz) && (threadIdx.x & 63) == 0) sh[wv] = 1;
  __syncthreads();
  if (threadIdx.x == 0) *flag = sh[0] | sh[1] | sh[2] | sh[3];
}

__device__ __forceinline__ int edge_src(const int* ei, int f, int i) {
  return f ? ei[i] : ei[2 * i];
}
__device__ __forceinline__ int edge_dst(const int* ei, int f, int i) {
  return f ? ei[N_EDGES + i] : ei[2 * (N_EDGES + i)];
}

// ---------------------------------------------------------------------------
// CSR build grouped by dst (range order irrelevant -> atomic range alloc)
// ---------------------------------------------------------------------------
__global__ __launch_bounds__(256) void k_count(const int* __restrict__ ei,
                                               const int* __restrict__ flag,
                                               int* __restrict__ deg) {
  int i = blockIdx.x * 256 + threadIdx.x;
  if (i >= E_TOT) return;
  int f = *flag;
  int d = (i < N_EDGES) ? edge_dst(ei, f, i) : (i - N_EDGES);
  atomicAdd(deg + d, 1);
}

__global__ __launch_bounds__(256) void k_alloc(const int* __restrict__ deg,
                                               int* __restrict__ off,
                                               int* __restrict__ pos,
                                               int* __restrict__ counter) {
  int i = blockIdx.x * 256 + threadIdx.x;
  if (i >= N_NODES) return;
  int r = atomicAdd(counter, deg[i]);
  off[i] = r;
  pos[i] = r;
}

__global__ __launch_bounds__(256) void k_fill(const int* __restrict__ ei,
                                              const int* __restrict__ flag,
                                              int* __restrict__ pos,
                                              int* __restrict__ csr_src) {
  int i = blockIdx.x * 256 + threadIdx.x;
  if (i >= E_TOT) return;
  int f = *flag;
  int s, d;
  if (i < N_EDGES) { s = edge_src(ei, f, i); d = edge_dst(ei, f, i); }
  else             { s = d = i - N_EDGES; }
  int slot = atomicAdd(pos + d, 1);
  csr_src[slot] = s;
}

// ---------------------------------------------------------------------------
// conversion kernels (one-shot, tiny)
// ---------------------------------------------------------------------------
__global__ __launch_bounds__(256) void k_cvt_x(const float* __restrict__ x,
                                               unsigned short* __restrict__ xb) {
  int i = blockIdx.x * 256 + threadIdx.x;
  if (i >= N_NODES * K1P) return;
  int row = i / K1P, col = i - row * K1P;
  float v = (col < FIN) ? x[(size_t)row * FIN + col] : 0.f;
  xb[i] = f2bf(v);
}

__global__ __launch_bounds__(256) void k_cvt_wt(const float* __restrict__ W,
                                                unsigned short* __restrict__ Wt,
                                                int K, int Kpad) {
  int i = blockIdx.x * 256 + threadIdx.x;
  if (i >= 512 * Kpad) return;
  int n = i / Kpad, k = i - n * Kpad;
  Wt[i] = f2bf(k < K ? W[(size_t)k * 512 + n] : 0.f);
}

// ---------------------------------------------------------------------------
// bf16 MFMA GEMM (m97 structure): C[M_PAD,512] = A[M_PAD,lda] @ Bt[512,lda]^T
// ---------------------------------------------------------------------------
template<bool BIAS_RELU>
__global__ __launch_bounds__(256)
void gemm_mfma(const unsigned short* __restrict__ A,
               const unsigned short* __restrict__ Bt,
               const float* __restrict__ bias,
               unsigned short* __restrict__ C,
               int lda)
{
  __shared__ unsigned short As[128 * 32];   // [m][k] 8 KB
  __shared__ unsigned short Bs[128 * 32];   // [n][k] 8 KB
  const int t    = threadIdx.x;
  const int w    = t >> 6;
  const int lane = t & 63;
  const int r    = lane & 15;
  const int q    = lane >> 4;
  const int bm   = blockIdx.y * 128;
  const int bn   = blockIdx.x * 128;
  const int wm   = (w >> 1) * 64;
  const int wn   = (w & 1) * 64;

  const int ch0 = (w * 2 + 0) * 64 + lane;
  const int ch1 = (w * 2 + 1) * 64 + lane;
  const unsigned short* gA0 = A + (size_t)(bm + (ch0 >> 2)) * lda + (ch0 & 3) * 8;
  const unsigned short* gA1 = A + (size_t)(bm + (ch1 >> 2)) * lda + (ch1 & 3) * 8;
  const unsigned short* gB0 = Bt + (size_t)(bn + (ch0 >> 2)) * lda + (ch0 & 3) * 8;
  const unsigned short* gB1 = Bt + (size_t)(bn + (ch1 >> 2)) * lda + (ch1 & 3) * 8;
  unsigned short* lA0 = As + (w * 2 + 0) * 512;
  unsigned short* lA1 = As + (w * 2 + 1) * 512;
  unsigned short* lB0 = Bs + (w * 2 + 0) * 512;
  unsigned short* lB1 = Bs + (w * 2 + 1) * 512;

  floatx4 acc[4][4] = {};

  for (int k0 = 0; k0 < lda; k0 += 32) {
    gll16(gA0 + k0, lA0);
    gll16(gA1 + k0, lA1);
    gll16(gB0 + k0, lB0);
    gll16(gB1 + k0, lB1);
    __syncthreads();

    short8 af[4], bfr[4];
#pragma unroll
    for (int im = 0; im < 4; ++im)
      af[im] = *(const short8*)(As + (wm + im * 16 + r) * 32 + q * 8);
#pragma unroll
    for (int in = 0; in < 4; ++in)
      bfr[in] = *(const short8*)(Bs + (wn + in * 16 + r) * 32 + q * 8);
#pragma unroll
    for (int im = 0; im < 4; ++im)
#pragma unroll
      for (int in = 0; in < 4; ++in)
        acc[im][in] = __builtin_amdgcn_mfma_f32_16x16x32_bf16(
            af[im], bfr[in], acc[im][in], 0, 0, 0);
    __syncthreads();
  }

  // epilogue: C/D layout col=lane&15, row=q*4+reg
#pragma unroll
  for (int in = 0; in < 4; ++in) {
    const int col = bn + wn + in * 16 + r;
    float bv = BIAS_RELU ? bias[col] : 0.f;
#pragma unroll
    for (int im = 0; im < 4; ++im) {
      const size_t rowbase = (size_t)(bm + wm + im * 16 + q * 4) * 512 + col;
#pragma unroll
      for (int rr = 0; rr < 4; ++rr) {
        float v = acc[im][in][rr];
        if (BIAS_RELU) v = fmaxf(v + bv, 0.f);
        C[rowbase + (size_t)rr * 512] = f2bf(v);
      }
    }
  }
}

// ---------------------------------------------------------------------------
// Per-node attention dots on bf16 h: s[n,h] = sum_c h[n,h*128+c]*a[h,c]
// ---------------------------------------------------------------------------
__global__ __launch_bounds__(256) void k_sdots(const unsigned short* __restrict__ h,
                                               const float* __restrict__ a_src,
                                               const float* __restrict__ a_dst,
                                               float* __restrict__ s_src,
                                               float* __restrict__ s_dst) {
  int node = blockIdx.x * 4 + (threadIdx.x >> 6);
  int lane = threadIdx.x & 63;
  if (node >= N_NODES) return;
  uint4 w = ((const uint4*)(h + (size_t)node * D))[lane];
  float v[8];
  unpack2(w.x, v[0], v[1]); unpack2(w.y, v[2], v[3]);
  unpack2(w.z, v[4], v[5]); unpack2(w.w, v[6], v[7]);
  const float4* as = (const float4*)a_src;
  const float4* ad = (const float4*)a_dst;
  float4 s0 = as[lane*2], s1 = as[lane*2+1];
  float4 d0 = ad[lane*2], d1 = ad[lane*2+1];
  float ps = v[0]*s0.x + v[1]*s0.y + v[2]*s0.z + v[3]*s0.w
           + v[4]*s1.x + v[5]*s1.y + v[6]*s1.z + v[7]*s1.w;
  float pd = v[0]*d0.x + v[1]*d0.y + v[2]*d0.z + v[3]*d0.w
           + v[4]*d1.x + v[5]*d1.y + v[6]*d1.z + v[7]*d1.w;
#pragma unroll
  for (int o = 1; o < 16; o <<= 1) {
    ps += __shfl_xor(ps, o);
    pd += __shfl_xor(pd, o);
  }
  if ((lane & 15) == 0) {
    int hh = lane >> 4;
    s_src[node*4 + hh] = ps;
    s_dst[node*4 + hh] = pd;
  }
}

// ---------------------------------------------------------------------------
// Fused segment-softmax + aggregation + bias + LayerNorm + ELU, SINGLE PASS.
// Softmax without max-shift (|e| <~ 10, fp32-safe; shift-invariant math):
//   out = (sum_j exp(e_j) * h[src_j]) / (sum_j exp(e_j))
// One wave per dst node; row gather software-pipelined one edge ahead.
// ---------------------------------------------------------------------------
__global__ __launch_bounds__(256) void k_aggregate(const unsigned short* __restrict__ h,
                                                   const int* __restrict__ csr_src,
                                                   const int* __restrict__ off,
                                                   const int* __restrict__ deg,
                                                   const float* __restrict__ s_src,
                                                   const float* __restrict__ s_dst,
                                                   const float* __restrict__ bvec,
                                                   const float* __restrict__ gvec,
                                                   const float* __restrict__ bevec,
                                                   unsigned short* __restrict__ out) {
  int node = blockIdx.x * 4 + (threadIdx.x >> 6);
  int lane = threadIdx.x & 63;
  if (node >= N_NODES) return;
  const int o   = __builtin_amdgcn_readfirstlane(off[node]);
  const int cnt = __builtin_amdgcn_readfirstlane(deg[node]);
  const int head = lane >> 4;
  const float sdH = s_dst[(size_t)node * 4 + head];

  float acc[8] = {0.f,0.f,0.f,0.f,0.f,0.f,0.f,0.f};
  float sum = 0.f;

  int s_cur = __builtin_amdgcn_readfirstlane(csr_src[o]);
  uint4 w_cur = ((const uint4*)(h + (size_t)s_cur * D))[lane];

  for (int j = 0; j < cnt; ++j) {
    int jn = (j + 1 < cnt) ? (j + 1) : j;
    int s_nxt = __builtin_amdgcn_readfirstlane(csr_src[o + jn]);
    uint4 w_nxt = ((const uint4*)(h + (size_t)s_nxt * D))[lane];

    float e = s_src[(size_t)s_cur * 4 + head] + sdH;
    e = (e > 0.f) ? e : NEG_SLOPE * e;
    float p = __expf(e);
    sum += p;
    float v[8];
    unpack2(w_cur.x, v[0], v[1]); unpack2(w_cur.y, v[2], v[3]);
    unpack2(w_cur.z, v[4], v[5]); unpack2(w_cur.w, v[6], v[7]);
#pragma unroll
    for (int k = 0; k < 8; ++k) acc[k] += p * v[k];

    s_cur = s_nxt;
    w_cur = w_nxt;
  }

  const float inv = 1.f / sum;
  const float4* bb = (const float4*)bvec;
  float4 b0 = bb[lane*2], b1 = bb[lane*2+1];
  float bl[8] = {b0.x,b0.y,b0.z,b0.w,b1.x,b1.y,b1.z,b1.w};
#pragma unroll
  for (int k = 0; k < 8; ++k) acc[k] = acc[k] * inv + bl[k];

  float ps = 0.f, pq = 0.f;
#pragma unroll
  for (int k = 0; k < 8; ++k) { ps += acc[k]; pq += acc[k]*acc[k]; }
#pragma unroll
  for (int o2 = 1; o2 < 64; o2 <<= 1) {
    ps += __shfl_xor(ps, o2);
    pq += __shfl_xor(pq, o2);
  }
  float mu  = ps * (1.f/512.f);
  float var = pq * (1.f/512.f) - mu*mu;
  float rstd = rsqrtf(var + LN_EPS);

  const float4* gg = (const float4*)gvec;
  const float4* ee = (const float4*)bevec;
  float4 g0 = gg[lane*2], g1 = gg[lane*2+1];
  float4 e0 = ee[lane*2], e1 = ee[lane*2+1];
  float gs[8] = {g0.x,g0.y,g0.z,g0.w,g1.x,g1.y,g1.z,g1.w};
  float es[8] = {e0.x,e0.y,e0.z,e0.w,e1.x,e1.y,e1.z,e1.w};

  unsigned short us[8];
#pragma unroll
  for (int k = 0; k < 8; ++k) {
    float y = (acc[k] - mu) * rstd * gs[k] + es[k];
    y = (y > 0.f) ? y : expm1f(y);
    us[k] = f2bf(y);
  }
  uint4 w;
  w.x = (unsigned int)us[0] | ((unsigned int)us[1] << 16);
  w.y = (unsigned int)us[2] | ((unsigned int)us[3] << 16);
  w.z = (unsigned int)us[4] | ((unsigned int)us[5] << 16);
  w.w = (unsigned int)us[6] | ((unsigned int)us[7] << 16);
  ((uint4*)(out + (size_t)node * D))[lane] = w;
}

// ---------------------------------------------------------------------------
// Final projection: out[n,0:2] = z[n,:] @ Wc2[512,2] + bc2 (z is bf16)
// ---------------------------------------------------------------------------
__global__ __launch_bounds__(256) void k_final(const unsigned short* __restrict__ z,
                                               const float* __restrict__ Wc2,
                                               const float* __restrict__ bc2,
                                               float* __restrict__ out) {
  int node = blockIdx.x * 4 + (threadIdx.x >> 6);
  int lane = threadIdx.x & 63;
  if (node >= N_NODES) return;
  uint4 w = ((const uint4*)(z + (size_t)node * D))[lane];
  float zv[8];
  unpack2(w.x, zv[0], zv[1]); unpack2(w.y, zv[2], zv[3]);
  unpack2(w.z, zv[4], zv[5]); unpack2(w.w, zv[6], zv[7]);
  const float* wr = Wc2 + (size_t)lane * 16;
  float a0 = 0.f, a1 = 0.f;
#pragma unroll
  for (int k = 0; k < 8; ++k) {
    a0 += zv[k] * wr[k*2];
    a1 += zv[k] * wr[k*2+1];
  }
#pragma unroll
  for (int o2 = 1; o2 < 64; o2 <<= 1) {
    a0 += __shfl_xor(a0, o2);
    a1 += __shfl_xor(a1, o2);
  }
  if (lane == 0) {
    out[(size_t)node*2]     = a0 + bc2[0];
    out[(size_t)node*2 + 1] = a1 + bc2[1];
  }
}

// ---------------------------------------------------------------------------
extern "C" void kernel_launch(void* const* d_in, const int* in_sizes, int n_in,
                              void* d_out, int out_size, void* d_ws, size_t ws_size,
                              hipStream_t stream) {
  const float* x      = (const float*)d_in[0];
  const int*   ei     = (const int*)  d_in[1];
  const float* W1     = (const float*)d_in[2];
  const float* a_src1 = (const float*)d_in[3];
  const float* a_dst1 = (const float*)d_in[4];
  const float* b1     = (const float*)d_in[5];
  const float* g1     = (const float*)d_in[6];
  const float* be1    = (const float*)d_in[7];
  const float* W2     = (const float*)d_in[8];
  const float* a_src2 = (const float*)d_in[9];
  const float* a_dst2 = (const float*)d_in[10];
  const float* b2     = (const float*)d_in[11];
  const float* g2     = (const float*)d_in[12];
  const float* be2    = (const float*)d_in[13];
  const float* Wc1    = (const float*)d_in[14];
  const float* bc1    = (const float*)d_in[15];
  const float* Wc2    = (const float*)d_in[16];
  const float* bc2    = (const float*)d_in[17];
  float* outp = (float*)d_out;

  char* p = (char*)d_ws;
  auto alloc = [&](size_t bytes) {
    char* r = p;
    p += (bytes + 255) & ~(size_t)255;
    return r;
  };
  unsigned short* hbuf = (unsigned short*)alloc((size_t)M_PAD * D * 2); // 102.5 MB
  unsigned short* obuf = (unsigned short*)alloc((size_t)M_PAD * D * 2); // 102.5 MB
  unsigned short* w1t  = (unsigned short*)alloc((size_t)512 * K1P * 2);
  unsigned short* w2t  = (unsigned short*)alloc((size_t)512 * 512 * 2);
  unsigned short* wc1t = (unsigned short*)alloc((size_t)512 * 512 * 2);
  int*   csr_src = (int*)  alloc((size_t)E_TOT * 4);                    // 6.8 MB
  int*   deg     = (int*)  alloc((size_t)N_NODES * 4);
  int*   off     = (int*)  alloc((size_t)N_NODES * 4);
  int*   pos     = (int*)  alloc((size_t)N_NODES * 4);
  int*   counter = (int*)  alloc(256);
  int*   flag    = (int*)  alloc(256);
  float* s_src   = (float*)alloc((size_t)N_NODES * 4 * 4);
  float* s_dst   = (float*)alloc((size_t)N_NODES * 4 * 4);
  // xb aliases obuf's first 38.4 MB (dead after GEMM-1, then overwritten)
  unsigned short* xb = obuf;

  const int EB = (E_TOT + 255) / 256;
  const int NB = (N_NODES + 255) / 256;
  const int NW = (N_NODES + 3) / 4;
  dim3 gg(4, M_PAD / 128);

  // init + dtype probe + CSR build + weight conversion
  k_init  <<<NB, 256, 0, stream>>>(deg, counter, flag);
  k_detect<<<1, 256, 0, stream>>>(ei, flag);
  k_count <<<EB, 256, 0, stream>>>(ei, flag, deg);
  k_alloc <<<NB, 256, 0, stream>>>(deg, off, pos, counter);
  k_fill  <<<EB, 256, 0, stream>>>(ei, flag, pos, csr_src);

  k_cvt_x <<<(N_NODES * K1P + 255) / 256, 256, 0, stream>>>(x, xb);
  k_cvt_wt<<<(512 * K1P + 255) / 256, 256, 0, stream>>>(W1, w1t, FIN, K1P);
  k_cvt_wt<<<(512 * 512 + 255) / 256, 256, 0, stream>>>(W2, w2t, 512, 512);
  k_cvt_wt<<<(512 * 512 + 255) / 256, 256, 0, stream>>>(Wc1, wc1t, 512, 512);

  // Layer 1
  gemm_mfma<false><<<gg, 256, 0, stream>>>(xb, w1t, nullptr, hbuf, K1P);
  k_sdots    <<<NW, 256, 0, stream>>>(hbuf, a_src1, a_dst1, s_src, s_dst);
  k_aggregate<<<NW, 256, 0, stream>>>(hbuf, csr_src, off, deg, s_src, s_dst, b1, g1, be1, obuf);

  // Layer 2
  gemm_mfma<false><<<gg, 256, 0, stream>>>(obuf, w2t, nullptr, hbuf, 512);
  k_sdots    <<<NW, 256, 0, stream>>>(hbuf, a_src2, a_dst2, s_src, s_dst);
  k_aggregate<<<NW, 256, 0, stream>>>(hbuf, csr_src, off, deg, s_src, s_dst, b2, g2, be2, obuf);

  // Classifier
  gemm_mfma<true><<<gg, 256, 0, stream>>>(obuf, wc1t, bc1, hbuf, 512);
  k_final    <<<NW, 256, 0, stream>>>(hbuf, Wc2, bc2, outp);
}